// Round 1
// baseline (5674.393 us; speedup 1.0000x reference)
//
#include <hip/hip_runtime.h>
#include <math.h>

#define N_NODES 50000
#define E_EDGES 800000
#define E_TOT   850000   // E + N self loops
#define HC 128
#define NHEAD 4
#define LIN 256
#define OUTC 10
#define NG 64
#define NEG_SLOPE 0.2f

// order-preserving float->uint key for atomicMax-based segment max
__device__ __forceinline__ unsigned fkey(float f) {
  unsigned u = __float_as_uint(f);
  return u ^ ((u & 0x80000000u) ? 0xFFFFFFFFu : 0x80000000u);
}
__device__ __forceinline__ float funkey(unsigned k) {
  unsigned u = (k & 0x80000000u) ? (k ^ 0x80000000u) : ~k;
  return __uint_as_float(u);
}
__device__ __forceinline__ float lrelu(float v) { return v > 0.f ? v : NEG_SLOPE * v; }

// h = x @ W  (N x 128 @ 128 x 128), plus per-node attention logits
// alpha_src[n,h] = sum_c h[n,h,c]*a_s[h,c], same for alpha_dst.
// Block: 256 threads = 32 rows x 8 threads; W staged in LDS (64 KB).
__global__ __launch_bounds__(256) void k_gemm_alpha(
    const float* __restrict__ x, const float* __restrict__ W,
    const float* __restrict__ a_s, const float* __restrict__ a_d,
    float* __restrict__ h, float* __restrict__ asrc, float* __restrict__ adst) {
  __shared__ float Ws[HC * HC];  // 64 KB
  int tid = threadIdx.x;
  {
    const float4* Wg = (const float4*)W;
    float4* Wv = (float4*)Ws;
#pragma unroll
    for (int i = 0; i < 16; i++) Wv[tid + i * 256] = Wg[tid + i * 256];
  }
  __syncthreads();
  int rl = tid >> 3, t = tid & 7;
  int row = blockIdx.x * 32 + rl;
  if (row >= N_NODES) return;
  const float4* xr = (const float4*)(x + row * HC);
  int c0 = t * 16;
  float acc[16];
#pragma unroll
  for (int j = 0; j < 16; j++) acc[j] = 0.f;
  for (int k4 = 0; k4 < HC / 4; k4++) {
    float4 xv4 = xr[k4];
#pragma unroll
    for (int kk = 0; kk < 4; kk++) {
      float xv = (kk == 0) ? xv4.x : (kk == 1) ? xv4.y : (kk == 2) ? xv4.z : xv4.w;
      int k = k4 * 4 + kk;
      const float4* wr = (const float4*)(Ws + k * HC + c0);
      float4 w0 = wr[0], w1 = wr[1], w2 = wr[2], w3 = wr[3];
      acc[0] += xv * w0.x; acc[1] += xv * w0.y; acc[2] += xv * w0.z; acc[3] += xv * w0.w;
      acc[4] += xv * w1.x; acc[5] += xv * w1.y; acc[6] += xv * w1.z; acc[7] += xv * w1.w;
      acc[8] += xv * w2.x; acc[9] += xv * w2.y; acc[10] += xv * w2.z; acc[11] += xv * w2.w;
      acc[12] += xv * w3.x; acc[13] += xv * w3.y; acc[14] += xv * w3.z; acc[15] += xv * w3.w;
    }
  }
  float4* hv = (float4*)(h + row * HC + c0);
  hv[0] = make_float4(acc[0], acc[1], acc[2], acc[3]);
  hv[1] = make_float4(acc[4], acc[5], acc[6], acc[7]);
  hv[2] = make_float4(acc[8], acc[9], acc[10], acc[11]);
  hv[3] = make_float4(acc[12], acc[13], acc[14], acc[15]);
  // attention logit partials: this thread covers head = t/2, channel offset (t&1)*16
  int head = t >> 1, o = (t & 1) * 16;
  float ps = 0.f, pd = 0.f;
#pragma unroll
  for (int j = 0; j < 16; j++) {
    ps += acc[j] * a_s[head * 32 + o + j];
    pd += acc[j] * a_d[head * 32 + o + j];
  }
  ps += __shfl_xor(ps, 1);
  pd += __shfl_xor(pd, 1);
  if ((t & 1) == 0) {
    asrc[row * NHEAD + head] = ps;
    adst[row * NHEAD + head] = pd;
  }
}

// pass 1: e = leaky_relu(asrc[src]+adst[dst]); segment max over dst via key atomicMax
__global__ __launch_bounds__(256) void k_edge_max(
    const int* __restrict__ src, const int* __restrict__ dst,
    const float* __restrict__ asrc, const float* __restrict__ adst,
    float* __restrict__ ebuf, unsigned* __restrict__ mkey) {
  int e = blockIdx.x * 256 + threadIdx.x;
  if (e >= E_TOT) return;
  int s, d;
  if (e < E_EDGES) { s = src[e]; d = dst[e]; } else { s = d = e - E_EDGES; }
  float4 a = ((const float4*)asrc)[s];
  float4 b = ((const float4*)adst)[d];
  float4 ev;
  ev.x = lrelu(a.x + b.x); ev.y = lrelu(a.y + b.y);
  ev.z = lrelu(a.z + b.z); ev.w = lrelu(a.w + b.w);
  ((float4*)ebuf)[e] = ev;
  unsigned* mk = mkey + d * NHEAD;
  atomicMax(mk + 0, fkey(ev.x));
  atomicMax(mk + 1, fkey(ev.y));
  atomicMax(mk + 2, fkey(ev.z));
  atomicMax(mk + 3, fkey(ev.w));
}

// pass 2: ex = exp(e - m[dst]); segment sum via atomicAdd
__global__ __launch_bounds__(256) void k_edge_exp(
    const int* __restrict__ dst, const unsigned* __restrict__ mkey,
    float* __restrict__ ebuf, float* __restrict__ denom) {
  int e = blockIdx.x * 256 + threadIdx.x;
  if (e >= E_TOT) return;
  int d = (e < E_EDGES) ? dst[e] : e - E_EDGES;
  float4 ev = ((const float4*)ebuf)[e];
  uint4 mk = ((const uint4*)mkey)[d];
  float4 ex;
  ex.x = expf(ev.x - funkey(mk.x));
  ex.y = expf(ev.y - funkey(mk.y));
  ex.z = expf(ev.z - funkey(mk.z));
  ex.w = expf(ev.w - funkey(mk.w));
  ((float4*)ebuf)[e] = ex;
  float* dn = denom + d * NHEAD;
  atomicAdd(dn + 0, ex.x);
  atomicAdd(dn + 1, ex.y);
  atomicAdd(dn + 2, ex.z);
  atomicAdd(dn + 3, ex.w);
}

// pass 3: acc[dst] += h[src] * attn ; 32 lanes per edge, 4 feats (float4) each
__global__ __launch_bounds__(256) void k_edge_aggr(
    const int* __restrict__ src, const int* __restrict__ dst,
    const float* __restrict__ ebuf, const float* __restrict__ denom,
    const float* __restrict__ h, float* __restrict__ acc) {
  int gid = blockIdx.x * 256 + threadIdx.x;
  int e = gid >> 5, lane = gid & 31;
  if (e >= E_TOT) return;
  int s, d;
  if (e < E_EDGES) { s = src[e]; d = dst[e]; } else { s = d = e - E_EDGES; }
  int head = lane >> 3;
  float attn = ebuf[e * NHEAD + head] / denom[d * NHEAD + head];
  float4 hv = ((const float4*)(h + s * HC))[lane];
  float* op = acc + d * HC + lane * 4;
  atomicAdd(op + 0, hv.x * attn);
  atomicAdd(op + 1, hv.y * attn);
  atomicAdd(op + 2, hv.z * attn);
  atomicAdd(op + 3, hv.w * attn);
}

// epilogue: out = relu(acc + b) in place; optionally feed global-max-pool
__global__ __launch_bounds__(256) void k_epilogue(
    float* __restrict__ acc, const float* __restrict__ bias,
    const int* __restrict__ batch, unsigned* __restrict__ pooled, int do_pool) {
  int i = blockIdx.x * 256 + threadIdx.x;
  if (i >= N_NODES * (HC / 4)) return;
  int nidx = i >> 5, f4 = i & 31;
  float4 v = ((float4*)acc)[i];
  float4 b = ((const float4*)bias)[f4];
  v.x = fmaxf(v.x + b.x, 0.f);
  v.y = fmaxf(v.y + b.y, 0.f);
  v.z = fmaxf(v.z + b.z, 0.f);
  v.w = fmaxf(v.w + b.w, 0.f);
  ((float4*)acc)[i] = v;
  if (do_pool) {
    int g = batch[nidx];
    unsigned* pp = pooled + g * HC + f4 * 4;
    // post-relu values are >= 0 so raw bit compare == float compare; init 0 also
    // matches the reference's where(isfinite, pooled, 0) empty-graph guard.
    atomicMax(pp + 0, __float_as_uint(v.x));
    atomicMax(pp + 1, __float_as_uint(v.y));
    atomicMax(pp + 2, __float_as_uint(v.z));
    atomicMax(pp + 3, __float_as_uint(v.w));
  }
}

// final head: out[g] = (pooled[g] @ Wlin + blin) @ Wout + bout ; 1 block per graph
__global__ __launch_bounds__(256) void k_mlp(
    const float* __restrict__ pooled, const float* __restrict__ Wlin,
    const float* __restrict__ blin, const float* __restrict__ Wout,
    const float* __restrict__ bout, float* __restrict__ out) {
  __shared__ float p[HC];
  __shared__ float z[LIN];
  int g = blockIdx.x, tid = threadIdx.x;
  if (tid < HC) p[tid] = pooled[g * HC + tid];
  __syncthreads();
  float zv = blin[tid];
  for (int k = 0; k < HC; k++) zv += p[k] * Wlin[k * LIN + tid];
  z[tid] = zv;
  __syncthreads();
  if (tid < OUTC) {
    float o = bout[tid];
    for (int k = 0; k < LIN; k++) o += z[k] * Wout[k * OUTC + tid];
    out[g * OUTC + tid] = o;
  }
}

extern "C" void kernel_launch(void* const* d_in, const int* in_sizes, int n_in,
                              void* d_out, int out_size, void* d_ws, size_t ws_size,
                              hipStream_t stream) {
  const float* x     = (const float*)d_in[0];
  const int*   ei    = (const int*)d_in[1];
  const int*   batch = (const int*)d_in[2];
  const float* Wl[3] = {(const float*)d_in[3], (const float*)d_in[7], (const float*)d_in[11]};
  const float* As[3] = {(const float*)d_in[4], (const float*)d_in[8], (const float*)d_in[12]};
  const float* Ad[3] = {(const float*)d_in[5], (const float*)d_in[9], (const float*)d_in[13]};
  const float* Bi[3] = {(const float*)d_in[6], (const float*)d_in[10], (const float*)d_in[14]};
  const float* Wlin  = (const float*)d_in[15];
  const float* blin  = (const float*)d_in[16];
  const float* Wout  = (const float*)d_in[17];
  const float* bout  = (const float*)d_in[18];
  float* out = (float*)d_out;

  // workspace layout (floats): total 17,008,192 floats = ~68 MB
  float* ws = (float*)d_ws;
  float*    h      = ws;                         // N*128
  float*    nodeA  = ws + 6400000;               // N*128 (acc, then layer output)
  float*    asrc   = ws + 12800000;              // N*4
  float*    adst   = ws + 13000000;              // N*4
  unsigned* mkey   = (unsigned*)(ws + 13200000); // N*4
  float*    denom  = ws + 13400000;              // N*4 (adjacent to mkey)
  float*    ebuf   = ws + 13600000;              // E_TOT*4
  unsigned* pooled = (unsigned*)(ws + 17000000); // 64*128

  const int* srcp = ei;
  const int* dstp = ei + E_EDGES;

  hipMemsetAsync(pooled, 0, NG * HC * sizeof(unsigned), stream);

  const float* lin_in = x;
  for (int L = 0; L < 3; L++) {
    k_gemm_alpha<<<(N_NODES + 31) / 32, 256, 0, stream>>>(
        lin_in, Wl[L], As[L], Ad[L], h, asrc, adst);
    // zero mkey + denom (adjacent) and the accumulator
    hipMemsetAsync(mkey, 0, 2 * N_NODES * NHEAD * sizeof(float), stream);
    hipMemsetAsync(nodeA, 0, (size_t)N_NODES * HC * sizeof(float), stream);
    k_edge_max<<<(E_TOT + 255) / 256, 256, 0, stream>>>(srcp, dstp, asrc, adst, ebuf, mkey);
    k_edge_exp<<<(E_TOT + 255) / 256, 256, 0, stream>>>(dstp, mkey, ebuf, denom);
    k_edge_aggr<<<(E_TOT * 32 + 255) / 256, 256, 0, stream>>>(srcp, dstp, ebuf, denom, h, nodeA);
    k_epilogue<<<(N_NODES * (HC / 4) + 255) / 256, 256, 0, stream>>>(
        nodeA, Bi[L], batch, pooled, (L == 2) ? 1 : 0);
    lin_in = nodeA;
  }
  k_mlp<<<NG, 256, 0, stream>>>((const float*)pooled, Wlin, blin, Wout, bout, out);
}

// Round 2
// 989.613 us; speedup vs baseline: 5.7340x; 5.7340x over previous
//
#include <hip/hip_runtime.h>
#include <math.h>

#define N_NODES 50000
#define E_EDGES 800000
#define E_TOT   850000   // E + N self loops
#define HC 128
#define NHEAD 4
#define LIN 256
#define OUTC 10
#define NG 64
#define NEG_SLOPE 0.2f

__device__ __forceinline__ float lrelu(float v) { return v > 0.f ? v : NEG_SLOPE * v; }

// ---------------------------------------------------------------------------
// GEMM + attention logits: h = x@W (N x128 @ 128x128); alpha_{src,dst}[n,h]
// Block: 256 threads = 32 rows x 8 threads; W staged in LDS (64 KB).
// ---------------------------------------------------------------------------
__global__ __launch_bounds__(256) void k_gemm_alpha(
    const float* __restrict__ x, const float* __restrict__ W,
    const float* __restrict__ a_s, const float* __restrict__ a_d,
    float* __restrict__ h, float* __restrict__ asrc, float* __restrict__ adst) {
  __shared__ float Ws[HC * HC];  // 64 KB
  int tid = threadIdx.x;
  {
    const float4* Wg = (const float4*)W;
    float4* Wv = (float4*)Ws;
#pragma unroll
    for (int i = 0; i < 16; i++) Wv[tid + i * 256] = Wg[tid + i * 256];
  }
  __syncthreads();
  int rl = tid >> 3, t = tid & 7;
  int row = blockIdx.x * 32 + rl;
  if (row >= N_NODES) return;
  const float4* xr = (const float4*)(x + row * HC);
  int c0 = t * 16;
  float acc[16];
#pragma unroll
  for (int j = 0; j < 16; j++) acc[j] = 0.f;
  for (int k4 = 0; k4 < HC / 4; k4++) {
    float4 xv4 = xr[k4];
#pragma unroll
    for (int kk = 0; kk < 4; kk++) {
      float xv = (kk == 0) ? xv4.x : (kk == 1) ? xv4.y : (kk == 2) ? xv4.z : xv4.w;
      int k = k4 * 4 + kk;
      const float4* wr = (const float4*)(Ws + k * HC + c0);
      float4 w0 = wr[0], w1 = wr[1], w2 = wr[2], w3 = wr[3];
      acc[0] += xv * w0.x; acc[1] += xv * w0.y; acc[2] += xv * w0.z; acc[3] += xv * w0.w;
      acc[4] += xv * w1.x; acc[5] += xv * w1.y; acc[6] += xv * w1.z; acc[7] += xv * w1.w;
      acc[8] += xv * w2.x; acc[9] += xv * w2.y; acc[10] += xv * w2.z; acc[11] += xv * w2.w;
      acc[12] += xv * w3.x; acc[13] += xv * w3.y; acc[14] += xv * w3.z; acc[15] += xv * w3.w;
    }
  }
  float4* hv = (float4*)(h + row * HC + c0);
  hv[0] = make_float4(acc[0], acc[1], acc[2], acc[3]);
  hv[1] = make_float4(acc[4], acc[5], acc[6], acc[7]);
  hv[2] = make_float4(acc[8], acc[9], acc[10], acc[11]);
  hv[3] = make_float4(acc[12], acc[13], acc[14], acc[15]);
  int head = t >> 1, o = (t & 1) * 16;
  float ps = 0.f, pd = 0.f;
#pragma unroll
  for (int j = 0; j < 16; j++) {
    ps += acc[j] * a_s[head * 32 + o + j];
    pd += acc[j] * a_d[head * 32 + o + j];
  }
  ps += __shfl_xor(ps, 1);
  pd += __shfl_xor(pd, 1);
  if ((t & 1) == 0) {
    asrc[row * NHEAD + head] = ps;
    adst[row * NHEAD + head] = pd;
  }
}

// ---------------------------------------------------------------------------
// CSR build: histogram -> exclusive scan -> scatter (int atomics only)
// ---------------------------------------------------------------------------
__global__ __launch_bounds__(256) void k_hist(
    const int* __restrict__ dst, int* __restrict__ deg) {
  int e = blockIdx.x * 256 + threadIdx.x;
  if (e >= E_TOT) return;
  int d = (e < E_EDGES) ? dst[e] : e - E_EDGES;
  atomicAdd(&deg[d], 1);
}

__global__ __launch_bounds__(1024) void k_scan(
    const int* __restrict__ deg, int* __restrict__ row_off) {
  __shared__ int ps[1024];
  int tid = threadIdx.x;
  const int CH = (N_NODES + 1023) / 1024;  // 49
  int base = tid * CH;
  int sum = 0;
  for (int i = 0; i < CH; i++) {
    int idx = base + i;
    if (idx < N_NODES) sum += deg[idx];
  }
  ps[tid] = sum;
  __syncthreads();
  for (int off = 1; off < 1024; off <<= 1) {
    int v = (tid >= off) ? ps[tid - off] : 0;
    __syncthreads();
    ps[tid] += v;
    __syncthreads();
  }
  int run = (tid ? ps[tid - 1] : 0);
  for (int i = 0; i < CH; i++) {
    int idx = base + i;
    if (idx < N_NODES) { row_off[idx] = run; run += deg[idx]; }
  }
  if (tid == 1023) row_off[N_NODES] = run;
}

__global__ __launch_bounds__(256) void k_scatter(
    const int* __restrict__ src, const int* __restrict__ dst,
    const int* __restrict__ row_off, int* __restrict__ cnt,
    int* __restrict__ csr_src) {
  int e = blockIdx.x * 256 + threadIdx.x;
  if (e >= E_TOT) return;
  int s, d;
  if (e < E_EDGES) { s = src[e]; d = dst[e]; } else { s = d = e - E_EDGES; }
  int pos = row_off[d] + atomicAdd(&cnt[d], 1);
  csr_src[pos] = s;
}

// ---------------------------------------------------------------------------
// Per-node online softmax stats over incoming edges: m[n,h], denom[n,h]
// One thread per node (avg degree ~17). No atomics, no edge buffer.
// ---------------------------------------------------------------------------
__global__ __launch_bounds__(256) void k_attn(
    const int* __restrict__ row_off, const int* __restrict__ csr_src,
    const float* __restrict__ asrc, const float* __restrict__ adst,
    float* __restrict__ mbuf, float* __restrict__ denom) {
  int n = blockIdx.x * 256 + threadIdx.x;
  if (n >= N_NODES) return;
  int lo = row_off[n], hi = row_off[n + 1];
  float4 ad = ((const float4*)adst)[n];
  float m[4] = {-1e30f, -1e30f, -1e30f, -1e30f};
  float s[4] = {0.f, 0.f, 0.f, 0.f};
  for (int j = lo; j < hi; j++) {
    int sidx = csr_src[j];
    float4 a = ((const float4*)asrc)[sidx];
    float e[4];
    e[0] = lrelu(a.x + ad.x); e[1] = lrelu(a.y + ad.y);
    e[2] = lrelu(a.z + ad.z); e[3] = lrelu(a.w + ad.w);
#pragma unroll
    for (int hd = 0; hd < 4; hd++) {
      if (e[hd] > m[hd]) {
        s[hd] = s[hd] * expf(m[hd] - e[hd]) + 1.f;
        m[hd] = e[hd];
      } else {
        s[hd] += expf(e[hd] - m[hd]);
      }
    }
  }
  ((float4*)mbuf)[n]  = make_float4(m[0], m[1], m[2], m[3]);
  ((float4*)denom)[n] = make_float4(s[0], s[1], s[2], s[3]);
}

// ---------------------------------------------------------------------------
// Aggregation, no atomics: one wave (64 lanes) per dst node; lane owns 2 feats.
// attn recomputed from (asrc, adst, m, denom) — VALU is idle, exp is free.
// Fused epilogue: bias + relu + (final layer) global-max-pool.
// ---------------------------------------------------------------------------
__global__ __launch_bounds__(256) void k_aggr(
    const int* __restrict__ row_off, const int* __restrict__ csr_src,
    const float* __restrict__ asrc, const float* __restrict__ adst,
    const float* __restrict__ mbuf, const float* __restrict__ denom,
    const float* __restrict__ h, const float* __restrict__ bias,
    const int* __restrict__ batch, float* __restrict__ out_h,
    unsigned* __restrict__ pooled, int do_pool) {
  int gid = blockIdx.x * 256 + threadIdx.x;
  int node = gid >> 6, lane = gid & 63;
  if (node >= N_NODES) return;
  int head = lane >> 4;  // feats lane*2, lane*2+1 belong to head (lane*2)/32
  int lo = row_off[node], hi = row_off[node + 1];
  float ad   = adst[node * NHEAD + head];
  float mh   = mbuf[node * NHEAD + head];
  float rden = 1.f / denom[node * NHEAD + head];
  float ax = 0.f, ay = 0.f;
  for (int j = lo; j < hi; j++) {
    int s = csr_src[j];  // wave-uniform
    float av = asrc[s * NHEAD + head];
    float attn = expf(lrelu(av + ad) - mh) * rden;
    float2 hv = *(const float2*)(h + s * HC + lane * 2);
    ax += attn * hv.x;
    ay += attn * hv.y;
  }
  float2 b = *(const float2*)(bias + lane * 2);
  float vx = fmaxf(ax + b.x, 0.f);
  float vy = fmaxf(ay + b.y, 0.f);
  *(float2*)(out_h + node * HC + lane * 2) = make_float2(vx, vy);
  if (do_pool) {
    int g = batch[node];
    unsigned* pp = pooled + g * HC + lane * 2;
    // post-relu values >= 0: bit compare == float compare; init 0 matches the
    // reference's where(isfinite, pooled, 0) empty-graph guard.
    atomicMax(pp + 0, __float_as_uint(vx));
    atomicMax(pp + 1, __float_as_uint(vy));
  }
}

// final head: out[g] = (pooled[g] @ Wlin + blin) @ Wout + bout ; 1 block/graph
__global__ __launch_bounds__(256) void k_mlp(
    const float* __restrict__ pooled, const float* __restrict__ Wlin,
    const float* __restrict__ blin, const float* __restrict__ Wout,
    const float* __restrict__ bout, float* __restrict__ out) {
  __shared__ float p[HC];
  __shared__ float z[LIN];
  int g = blockIdx.x, tid = threadIdx.x;
  if (tid < HC) p[tid] = pooled[g * HC + tid];
  __syncthreads();
  float zv = blin[tid];
  for (int k = 0; k < HC; k++) zv += p[k] * Wlin[k * LIN + tid];
  z[tid] = zv;
  __syncthreads();
  if (tid < OUTC) {
    float o = bout[tid];
    for (int k = 0; k < LIN; k++) o += z[k] * Wout[k * OUTC + tid];
    out[g * OUTC + tid] = o;
  }
}

extern "C" void kernel_launch(void* const* d_in, const int* in_sizes, int n_in,
                              void* d_out, int out_size, void* d_ws, size_t ws_size,
                              hipStream_t stream) {
  const float* x     = (const float*)d_in[0];
  const int*   ei    = (const int*)d_in[1];
  const int*   batch = (const int*)d_in[2];
  const float* Wl[3] = {(const float*)d_in[3], (const float*)d_in[7], (const float*)d_in[11]};
  const float* As[3] = {(const float*)d_in[4], (const float*)d_in[8], (const float*)d_in[12]};
  const float* Ad[3] = {(const float*)d_in[5], (const float*)d_in[9], (const float*)d_in[13]};
  const float* Bi[3] = {(const float*)d_in[6], (const float*)d_in[10], (const float*)d_in[14]};
  const float* Wlin  = (const float*)d_in[15];
  const float* blin  = (const float*)d_in[16];
  const float* Wout  = (const float*)d_in[17];
  const float* bout  = (const float*)d_in[18];
  float* out = (float*)d_out;

  // workspace layout (float offsets), total ~14.61M floats = ~58.4 MB
  float* ws = (float*)d_ws;
  float*    h       = ws;                          // N*128
  float*    nodeB   = ws + 6400000;                // N*128
  float*    asrc    = ws + 12800000;               // N*4
  float*    adst    = ws + 13000000;               // N*4
  float*    mbuf    = ws + 13200000;               // N*4
  float*    denom   = ws + 13400000;               // N*4
  int*      deg     = (int*)(ws + 13600000);       // N
  int*      cnt     = (int*)(ws + 13650000);       // N (adjacent to deg)
  int*      row_off = (int*)(ws + 13700000);       // N+1
  int*      csr_src = (int*)(ws + 13750008);       // E_TOT
  unsigned* pooled  = (unsigned*)(ws + 14600008);  // 64*128

  const int* srcp = ei;
  const int* dstp = ei + E_EDGES;

  // zero deg+cnt (adjacent) and pooled
  hipMemsetAsync(deg, 0, 2 * N_NODES * sizeof(int), stream);
  hipMemsetAsync(pooled, 0, NG * HC * sizeof(unsigned), stream);

  // CSR by dst — built once, reused by all 3 layers
  k_hist<<<(E_TOT + 255) / 256, 256, 0, stream>>>(dstp, deg);
  k_scan<<<1, 1024, 0, stream>>>(deg, row_off);
  k_scatter<<<(E_TOT + 255) / 256, 256, 0, stream>>>(srcp, dstp, row_off, cnt, csr_src);

  const float* lin_in = x;
  for (int L = 0; L < 3; L++) {
    k_gemm_alpha<<<(N_NODES + 31) / 32, 256, 0, stream>>>(
        lin_in, Wl[L], As[L], Ad[L], h, asrc, adst);
    k_attn<<<(N_NODES + 255) / 256, 256, 0, stream>>>(
        row_off, csr_src, asrc, adst, mbuf, denom);
    k_aggr<<<(N_NODES * 64 + 255) / 256, 256, 0, stream>>>(
        row_off, csr_src, asrc, adst, mbuf, denom, h, Bi[L], batch,
        nodeB, pooled, (L == 2) ? 1 : 0);
    lin_in = nodeB;
  }
  k_mlp<<<NG, 256, 0, stream>>>((const float*)pooled, Wlin, blin, Wout, bout, out);
}

// Round 3
// 769.807 us; speedup vs baseline: 7.3712x; 1.2855x over previous
//
#include <hip/hip_runtime.h>
#include <math.h>

#define N_NODES 50000
#define E_EDGES 800000
#define E_TOT   850000   // E + N self loops
#define HC 128
#define NHEAD 4
#define LIN 256
#define OUTC 10
#define NG 64
#define NEG_SLOPE 0.2f

__device__ __forceinline__ float lrelu(float v) { return v > 0.f ? v : NEG_SLOPE * v; }

// ---------------------------------------------------------------------------
// GEMM + attention logits: h = x@W (N x128 @ 128x128); alpha_{src,dst}[n,h]
// Block: 256 threads = 32 rows x 8 threads; W staged in LDS (64 KB).
// ---------------------------------------------------------------------------
__global__ __launch_bounds__(256) void k_gemm_alpha(
    const float* __restrict__ x, const float* __restrict__ W,
    const float* __restrict__ a_s, const float* __restrict__ a_d,
    float* __restrict__ h, float* __restrict__ asrc, float* __restrict__ adst) {
  __shared__ float Ws[HC * HC];  // 64 KB
  int tid = threadIdx.x;
  {
    const float4* Wg = (const float4*)W;
    float4* Wv = (float4*)Ws;
#pragma unroll
    for (int i = 0; i < 16; i++) Wv[tid + i * 256] = Wg[tid + i * 256];
  }
  __syncthreads();
  int rl = tid >> 3, t = tid & 7;
  int row = blockIdx.x * 32 + rl;
  if (row >= N_NODES) return;
  const float4* xr = (const float4*)(x + row * HC);
  int c0 = t * 16;
  float acc[16];
#pragma unroll
  for (int j = 0; j < 16; j++) acc[j] = 0.f;
  for (int k4 = 0; k4 < HC / 4; k4++) {
    float4 xv4 = xr[k4];
#pragma unroll
    for (int kk = 0; kk < 4; kk++) {
      float xv = (kk == 0) ? xv4.x : (kk == 1) ? xv4.y : (kk == 2) ? xv4.z : xv4.w;
      int k = k4 * 4 + kk;
      const float4* wr = (const float4*)(Ws + k * HC + c0);
      float4 w0 = wr[0], w1 = wr[1], w2 = wr[2], w3 = wr[3];
      acc[0] += xv * w0.x; acc[1] += xv * w0.y; acc[2] += xv * w0.z; acc[3] += xv * w0.w;
      acc[4] += xv * w1.x; acc[5] += xv * w1.y; acc[6] += xv * w1.z; acc[7] += xv * w1.w;
      acc[8] += xv * w2.x; acc[9] += xv * w2.y; acc[10] += xv * w2.z; acc[11] += xv * w2.w;
      acc[12] += xv * w3.x; acc[13] += xv * w3.y; acc[14] += xv * w3.z; acc[15] += xv * w3.w;
    }
  }
  float4* hv = (float4*)(h + row * HC + c0);
  hv[0] = make_float4(acc[0], acc[1], acc[2], acc[3]);
  hv[1] = make_float4(acc[4], acc[5], acc[6], acc[7]);
  hv[2] = make_float4(acc[8], acc[9], acc[10], acc[11]);
  hv[3] = make_float4(acc[12], acc[13], acc[14], acc[15]);
  int head = t >> 1, o = (t & 1) * 16;
  float ps = 0.f, pd = 0.f;
#pragma unroll
  for (int j = 0; j < 16; j++) {
    ps += acc[j] * a_s[head * 32 + o + j];
    pd += acc[j] * a_d[head * 32 + o + j];
  }
  ps += __shfl_xor(ps, 1);
  pd += __shfl_xor(pd, 1);
  if ((t & 1) == 0) {
    asrc[row * NHEAD + head] = ps;
    adst[row * NHEAD + head] = pd;
  }
}

// ---------------------------------------------------------------------------
// CSR build: histogram -> exclusive scan -> scatter (int atomics only)
// ---------------------------------------------------------------------------
__global__ __launch_bounds__(256) void k_hist(
    const int* __restrict__ dst, int* __restrict__ deg) {
  int e = blockIdx.x * 256 + threadIdx.x;
  if (e >= E_TOT) return;
  int d = (e < E_EDGES) ? dst[e] : e - E_EDGES;
  atomicAdd(&deg[d], 1);
}

__global__ __launch_bounds__(1024) void k_scan(
    const int* __restrict__ deg, int* __restrict__ row_off) {
  __shared__ int ps[1024];
  int tid = threadIdx.x;
  const int CH = (N_NODES + 1023) / 1024;  // 49
  int base = tid * CH;
  int sum = 0;
  for (int i = 0; i < CH; i++) {
    int idx = base + i;
    if (idx < N_NODES) sum += deg[idx];
  }
  ps[tid] = sum;
  __syncthreads();
  for (int off = 1; off < 1024; off <<= 1) {
    int v = (tid >= off) ? ps[tid - off] : 0;
    __syncthreads();
    ps[tid] += v;
    __syncthreads();
  }
  int run = (tid ? ps[tid - 1] : 0);
  for (int i = 0; i < CH; i++) {
    int idx = base + i;
    if (idx < N_NODES) { row_off[idx] = run; run += deg[idx]; }
  }
  if (tid == 1023) row_off[N_NODES] = run;
}

__global__ __launch_bounds__(256) void k_scatter(
    const int* __restrict__ src, const int* __restrict__ dst,
    const int* __restrict__ row_off, int* __restrict__ cnt,
    int* __restrict__ csr_src) {
  int e = blockIdx.x * 256 + threadIdx.x;
  if (e >= E_TOT) return;
  int s, d;
  if (e < E_EDGES) { s = src[e]; d = dst[e]; } else { s = d = e - E_EDGES; }
  int pos = row_off[d] + atomicAdd(&cnt[d], 1);
  csr_src[pos] = s;
}

// ---------------------------------------------------------------------------
// Fused softmax-stats + aggregation, no atomics except pool.
// One wave (64 lanes) per dst node; lane owns 2 feats; head = lane/16.
// Stage 1: the 16 lanes of each head group run per-lane online softmax over
//          edges strided by 16, then shuffle-combine -> (m, denom).
// Stage 2: edge loop unrolled x4 -> 4 independent 512B h-gathers in flight.
// Fused epilogue: bias + relu + (final layer) global-max-pool.
// ---------------------------------------------------------------------------
__global__ __launch_bounds__(256) void k_aggr(
    const int* __restrict__ row_off, const int* __restrict__ csr_src,
    const float* __restrict__ asrc, const float* __restrict__ adst,
    const float* __restrict__ h, const float* __restrict__ bias,
    const int* __restrict__ batch, float* __restrict__ out_h,
    unsigned* __restrict__ pooled, int do_pool) {
  int gid = blockIdx.x * 256 + threadIdx.x;
  int node = gid >> 6, lane = gid & 63;
  if (node >= N_NODES) return;
  int head = lane >> 4, l2 = lane & 15;
  int lo = row_off[node], hi = row_off[node + 1];
  float ad = adst[node * NHEAD + head];

  // --- stage 1: online softmax stats (per head, 16 lanes cooperate) ---
  float m = -1e30f, s = 0.f;
  for (int j = lo + l2; j < hi; j += 16) {
    int sv = csr_src[j];
    float e = lrelu(asrc[sv * NHEAD + head] + ad);
    if (e > m) {
      s = s * expf(m - e) + 1.f;
      m = e;
    } else {
      s += expf(e - m);
    }
  }
#pragma unroll
  for (int off = 1; off <= 8; off <<= 1) {
    float mo = __shfl_xor(m, off);
    float so = __shfl_xor(s, off);
    float mn = fmaxf(m, mo);
    s = s * expf(m - mn) + so * expf(mo - mn);
    m = mn;
  }
  float rden = 1.f / s;

  // --- stage 2: weighted aggregation, unrolled x4 for MLP ---
  float ax = 0.f, ay = 0.f;
  int j = lo;
  for (; j + 4 <= hi; j += 4) {
    int s0 = csr_src[j + 0], s1 = csr_src[j + 1];
    int s2 = csr_src[j + 2], s3 = csr_src[j + 3];
    float a0 = asrc[s0 * NHEAD + head], a1 = asrc[s1 * NHEAD + head];
    float a2 = asrc[s2 * NHEAD + head], a3 = asrc[s3 * NHEAD + head];
    float2 h0 = *(const float2*)(h + s0 * HC + lane * 2);
    float2 h1 = *(const float2*)(h + s1 * HC + lane * 2);
    float2 h2 = *(const float2*)(h + s2 * HC + lane * 2);
    float2 h3 = *(const float2*)(h + s3 * HC + lane * 2);
    float t0 = expf(lrelu(a0 + ad) - m);
    float t1 = expf(lrelu(a1 + ad) - m);
    float t2 = expf(lrelu(a2 + ad) - m);
    float t3 = expf(lrelu(a3 + ad) - m);
    ax += t0 * h0.x; ay += t0 * h0.y;
    ax += t1 * h1.x; ay += t1 * h1.y;
    ax += t2 * h2.x; ay += t2 * h2.y;
    ax += t3 * h3.x; ay += t3 * h3.y;
  }
  for (; j < hi; j++) {
    int sv = csr_src[j];
    float av = asrc[sv * NHEAD + head];
    float t = expf(lrelu(av + ad) - m);
    float2 hv = *(const float2*)(h + sv * HC + lane * 2);
    ax += t * hv.x; ay += t * hv.y;
  }
  ax *= rden; ay *= rden;

  float2 b = *(const float2*)(bias + lane * 2);
  float vx = fmaxf(ax + b.x, 0.f);
  float vy = fmaxf(ay + b.y, 0.f);
  *(float2*)(out_h + node * HC + lane * 2) = make_float2(vx, vy);
  if (do_pool) {
    int g = batch[node];
    unsigned* pp = pooled + g * HC + lane * 2;
    // post-relu values >= 0: bit compare == float compare; init 0 matches the
    // reference's where(isfinite, pooled, 0) empty-graph guard.
    atomicMax(pp + 0, __float_as_uint(vx));
    atomicMax(pp + 1, __float_as_uint(vy));
  }
}

// final head: out[g] = (pooled[g] @ Wlin + blin) @ Wout + bout ; 1 block/graph
__global__ __launch_bounds__(256) void k_mlp(
    const float* __restrict__ pooled, const float* __restrict__ Wlin,
    const float* __restrict__ blin, const float* __restrict__ Wout,
    const float* __restrict__ bout, float* __restrict__ out) {
  __shared__ float p[HC];
  __shared__ float z[LIN];
  int g = blockIdx.x, tid = threadIdx.x;
  if (tid < HC) p[tid] = pooled[g * HC + tid];
  __syncthreads();
  float zv = blin[tid];
  for (int k = 0; k < HC; k++) zv += p[k] * Wlin[k * LIN + tid];
  z[tid] = zv;
  __syncthreads();
  if (tid < OUTC) {
    float o = bout[tid];
    for (int k = 0; k < LIN; k++) o += z[k] * Wout[k * OUTC + tid];
    out[g * OUTC + tid] = o;
  }
}

extern "C" void kernel_launch(void* const* d_in, const int* in_sizes, int n_in,
                              void* d_out, int out_size, void* d_ws, size_t ws_size,
                              hipStream_t stream) {
  const float* x     = (const float*)d_in[0];
  const int*   ei    = (const int*)d_in[1];
  const int*   batch = (const int*)d_in[2];
  const float* Wl[3] = {(const float*)d_in[3], (const float*)d_in[7], (const float*)d_in[11]};
  const float* As[3] = {(const float*)d_in[4], (const float*)d_in[8], (const float*)d_in[12]};
  const float* Ad[3] = {(const float*)d_in[5], (const float*)d_in[9], (const float*)d_in[13]};
  const float* Bi[3] = {(const float*)d_in[6], (const float*)d_in[10], (const float*)d_in[14]};
  const float* Wlin  = (const float*)d_in[15];
  const float* blin  = (const float*)d_in[16];
  const float* Wout  = (const float*)d_in[17];
  const float* bout  = (const float*)d_in[18];
  float* out = (float*)d_out;

  // workspace layout (float offsets), total ~14.21M floats = ~56.8 MB
  float* ws = (float*)d_ws;
  float*    h       = ws;                          // N*128
  float*    nodeB   = ws + 6400000;                // N*128
  float*    asrc    = ws + 12800000;               // N*4
  float*    adst    = ws + 13000000;               // N*4
  int*      deg     = (int*)(ws + 13200000);       // N
  int*      cnt     = (int*)(ws + 13250000);       // N (adjacent to deg)
  int*      row_off = (int*)(ws + 13300000);       // N+1
  int*      csr_src = (int*)(ws + 13350008);       // E_TOT
  unsigned* pooled  = (unsigned*)(ws + 14200008);  // 64*128

  const int* srcp = ei;
  const int* dstp = ei + E_EDGES;

  // zero deg+cnt (adjacent) and pooled
  hipMemsetAsync(deg, 0, 2 * N_NODES * sizeof(int), stream);
  hipMemsetAsync(pooled, 0, NG * HC * sizeof(unsigned), stream);

  // CSR by dst — built once, reused by all 3 layers
  k_hist<<<(E_TOT + 255) / 256, 256, 0, stream>>>(dstp, deg);
  k_scan<<<1, 1024, 0, stream>>>(deg, row_off);
  k_scatter<<<(E_TOT + 255) / 256, 256, 0, stream>>>(srcp, dstp, row_off, cnt, csr_src);

  const float* lin_in = x;
  for (int L = 0; L < 3; L++) {
    k_gemm_alpha<<<(N_NODES + 31) / 32, 256, 0, stream>>>(
        lin_in, Wl[L], As[L], Ad[L], h, asrc, adst);
    k_aggr<<<(N_NODES * 64 + 255) / 256, 256, 0, stream>>>(
        row_off, csr_src, asrc, adst, h, Bi[L], batch,
        nodeB, pooled, (L == 2) ? 1 : 0);
    lin_in = nodeB;
  }
  k_mlp<<<NG, 256, 0, stream>>>((const float*)pooled, Wlin, blin, Wout, bout, out);
}

// Round 4
// 662.048 us; speedup vs baseline: 8.5710x; 1.1628x over previous
//
#include <hip/hip_runtime.h>
#include <math.h>

#define N_NODES 50000
#define E_EDGES 800000
#define E_TOT   850000   // E + N self loops
#define HC 128
#define NHEAD 4
#define LIN 256
#define OUTC 10
#define NG 64
#define NEG_SLOPE 0.2f

__device__ __forceinline__ float lrelu(float v) { return v > 0.f ? v : NEG_SLOPE * v; }

// ---------------------------------------------------------------------------
// GEMM + attention logits: h = x@W (N x128 @ 128x128); alpha_{src,dst}[n,h].
// 4 rows x 16 cols per thread; cols interleaved (c = t*4 + 32u) so each
// ds_read_b128 hits all 32 banks conflict-free (old t*16 layout was 4-way).
// Block: 256 threads = 128 rows; W staged once in LDS (64 KB).
// ---------------------------------------------------------------------------
__global__ __launch_bounds__(256, 2) void k_gemm_alpha(
    const float* __restrict__ x, const float* __restrict__ W,
    const float* __restrict__ a_s, const float* __restrict__ a_d,
    float* __restrict__ h, float* __restrict__ asrc, float* __restrict__ adst) {
  __shared__ float Ws[HC * HC];  // 64 KB
  int tid = threadIdx.x;
  {
    const float4* Wg = (const float4*)W;
    float4* Wv = (float4*)Ws;
#pragma unroll
    for (int i = 0; i < 16; i++) Wv[tid + i * 256] = Wg[tid + i * 256];
  }
  __syncthreads();
  int rl = tid >> 3, t = tid & 7;
  int base = blockIdx.x * 128;
  int row[4];
  const float4* xr[4];
#pragma unroll
  for (int r = 0; r < 4; r++) {
    row[r] = base + rl + 32 * r;
    int rc = row[r] < N_NODES ? row[r] : N_NODES - 1;  // clamp, store-guarded
    xr[r] = (const float4*)(x + (size_t)rc * HC);
  }
  float acc[4][16];
#pragma unroll
  for (int r = 0; r < 4; r++)
#pragma unroll
    for (int j = 0; j < 16; j++) acc[r][j] = 0.f;

  for (int k4 = 0; k4 < 32; k4++) {
    float4 xa = xr[0][k4], xb = xr[1][k4], xc = xr[2][k4], xd = xr[3][k4];
#pragma unroll
    for (int kk = 0; kk < 4; kk++) {
      const float* wb = Ws + (k4 * 4 + kk) * HC + t * 4;
      float4 w0 = *(const float4*)(wb);
      float4 w1 = *(const float4*)(wb + 32);
      float4 w2 = *(const float4*)(wb + 64);
      float4 w3 = *(const float4*)(wb + 96);
      float xs[4];
      xs[0] = (kk == 0) ? xa.x : (kk == 1) ? xa.y : (kk == 2) ? xa.z : xa.w;
      xs[1] = (kk == 0) ? xb.x : (kk == 1) ? xb.y : (kk == 2) ? xb.z : xb.w;
      xs[2] = (kk == 0) ? xc.x : (kk == 1) ? xc.y : (kk == 2) ? xc.z : xc.w;
      xs[3] = (kk == 0) ? xd.x : (kk == 1) ? xd.y : (kk == 2) ? xd.z : xd.w;
#pragma unroll
      for (int r = 0; r < 4; r++) {
        float xv = xs[r];
        acc[r][0] += xv * w0.x;  acc[r][1] += xv * w0.y;
        acc[r][2] += xv * w0.z;  acc[r][3] += xv * w0.w;
        acc[r][4] += xv * w1.x;  acc[r][5] += xv * w1.y;
        acc[r][6] += xv * w1.z;  acc[r][7] += xv * w1.w;
        acc[r][8] += xv * w2.x;  acc[r][9] += xv * w2.y;
        acc[r][10] += xv * w2.z; acc[r][11] += xv * w2.w;
        acc[r][12] += xv * w3.x; acc[r][13] += xv * w3.y;
        acc[r][14] += xv * w3.z; acc[r][15] += xv * w3.w;
      }
    }
  }

#pragma unroll
  for (int r = 0; r < 4; r++) {
    // col c = t*4 + 32u + j  ->  head = u, channel = t*4 + j
    float ps[4], pd[4];
#pragma unroll
    for (int u = 0; u < 4; u++) {
      float s = 0.f, d = 0.f;
#pragma unroll
      for (int j = 0; j < 4; j++) {
        float av = acc[r][u * 4 + j];
        s += av * a_s[u * 32 + t * 4 + j];
        d += av * a_d[u * 32 + t * 4 + j];
      }
      s += __shfl_xor(s, 1); s += __shfl_xor(s, 2); s += __shfl_xor(s, 4);
      d += __shfl_xor(d, 1); d += __shfl_xor(d, 2); d += __shfl_xor(d, 4);
      ps[u] = s; pd[u] = d;
    }
    if (row[r] < N_NODES) {
      float* hr = h + (size_t)row[r] * HC;
#pragma unroll
      for (int u = 0; u < 4; u++)
        *(float4*)(hr + t * 4 + 32 * u) = make_float4(
            acc[r][u * 4 + 0], acc[r][u * 4 + 1], acc[r][u * 4 + 2], acc[r][u * 4 + 3]);
      if (t < 4) {
        float vs = (t == 0) ? ps[0] : (t == 1) ? ps[1] : (t == 2) ? ps[2] : ps[3];
        float vd = (t == 0) ? pd[0] : (t == 1) ? pd[1] : (t == 2) ? pd[2] : pd[3];
        asrc[row[r] * NHEAD + t] = vs;
        adst[row[r] * NHEAD + t] = vd;
      }
    }
  }
}

// ---------------------------------------------------------------------------
// CSR build: histogram -> exclusive scan -> scatter (int atomics only)
// ---------------------------------------------------------------------------
__global__ __launch_bounds__(256) void k_hist(
    const int* __restrict__ dst, int* __restrict__ deg) {
  int e = blockIdx.x * 256 + threadIdx.x;
  if (e >= E_TOT) return;
  int d = (e < E_EDGES) ? dst[e] : e - E_EDGES;
  atomicAdd(&deg[d], 1);
}

__global__ __launch_bounds__(1024) void k_scan(
    const int* __restrict__ deg, int* __restrict__ row_off) {
  __shared__ int ps[1024];
  int tid = threadIdx.x;
  const int CH = (N_NODES + 1023) / 1024;  // 49
  int base = tid * CH;
  int sum = 0;
  for (int i = 0; i < CH; i++) {
    int idx = base + i;
    if (idx < N_NODES) sum += deg[idx];
  }
  ps[tid] = sum;
  __syncthreads();
  for (int off = 1; off < 1024; off <<= 1) {
    int v = (tid >= off) ? ps[tid - off] : 0;
    __syncthreads();
    ps[tid] += v;
    __syncthreads();
  }
  int run = (tid ? ps[tid - 1] : 0);
  for (int i = 0; i < CH; i++) {
    int idx = base + i;
    if (idx < N_NODES) { row_off[idx] = run; run += deg[idx]; }
  }
  if (tid == 1023) row_off[N_NODES] = run;
}

__global__ __launch_bounds__(256) void k_scatter(
    const int* __restrict__ src, const int* __restrict__ dst,
    const int* __restrict__ row_off, int* __restrict__ cnt,
    int* __restrict__ csr_src) {
  int e = blockIdx.x * 256 + threadIdx.x;
  if (e >= E_TOT) return;
  int s, d;
  if (e < E_EDGES) { s = src[e]; d = dst[e]; } else { s = d = e - E_EDGES; }
  int pos = row_off[d] + atomicAdd(&cnt[d], 1);
  csr_src[pos] = s;
}

#define BFLY_MAX4(m0, m1, m2, m3)                         \
  _Pragma("unroll") for (int off = 1; off < 64; off <<= 1) { \
    m0 = fmaxf(m0, __shfl_xor(m0, off));                  \
    m1 = fmaxf(m1, __shfl_xor(m1, off));                  \
    m2 = fmaxf(m2, __shfl_xor(m2, off));                  \
    m3 = fmaxf(m3, __shfl_xor(m3, off));                  \
  }
#define BFLY_SUM4(s0, s1, s2, s3)                         \
  _Pragma("unroll") for (int off = 1; off < 64; off <<= 1) { \
    s0 += __shfl_xor(s0, off);                            \
    s1 += __shfl_xor(s1, off);                            \
    s2 += __shfl_xor(s2, off);                            \
    s3 += __shfl_xor(s3, off);                            \
  }

// ---------------------------------------------------------------------------
// Fused softmax + aggregation. One wave per dst node; lane owns 2 feats.
// Batched: lane j loads edge j's index + asrc once (coalesced/gather),
// softmax stats via butterfly shuffles, per-edge weights parked in LDS.
// Aggregation loop reads indices/weights from LDS (cheap) -> all h-gathers
// issue independently. Fused bias+relu+(final) max-pool epilogue.
// ---------------------------------------------------------------------------
__global__ __launch_bounds__(256) void k_aggr(
    const int* __restrict__ row_off, const int* __restrict__ csr_src,
    const float* __restrict__ asrc, const float* __restrict__ adst,
    const float* __restrict__ h, const float* __restrict__ bias,
    const int* __restrict__ batch, float* __restrict__ out_h,
    unsigned* __restrict__ pooled, int do_pool) {
  __shared__ int   sv_lds[4][64];
  __shared__ float w_lds[4][64][4];
  int gid = blockIdx.x * 256 + threadIdx.x;
  int node = gid >> 6, lane = gid & 63, wl = threadIdx.x >> 6;
  if (node >= N_NODES) return;
  int head = lane >> 4;
  int lo = row_off[node], hi = row_off[node + 1];
  int deg = hi - lo;
  float4 ad4 = ((const float4*)adst)[node];  // broadcast
  float ax = 0.f, ay = 0.f;
  float S;

  if (deg <= 64) {
    int j = lo + lane;
    int sv = (j < hi) ? csr_src[j] : 0;
    float4 a4 = ((const float4*)asrc)[sv];
    bool valid = (j < hi);
    float e0 = valid ? lrelu(a4.x + ad4.x) : -1e30f;
    float e1 = valid ? lrelu(a4.y + ad4.y) : -1e30f;
    float e2 = valid ? lrelu(a4.z + ad4.z) : -1e30f;
    float e3 = valid ? lrelu(a4.w + ad4.w) : -1e30f;
    float m0 = e0, m1 = e1, m2 = e2, m3 = e3;
    BFLY_MAX4(m0, m1, m2, m3)
    float w0 = expf(e0 - m0), w1 = expf(e1 - m1);
    float w2 = expf(e2 - m2), w3 = expf(e3 - m3);  // invalid lanes -> 0
    float s0 = w0, s1 = w1, s2 = w2, s3 = w3;
    BFLY_SUM4(s0, s1, s2, s3)
    sv_lds[wl][lane] = sv;
    *(float4*)&w_lds[wl][lane][0] = make_float4(w0, w1, w2, w3);
    S = (head == 0) ? s0 : (head == 1) ? s1 : (head == 2) ? s2 : s3;
    int jj = 0;
    for (; jj + 4 <= deg; jj += 4) {
      int i0 = sv_lds[wl][jj + 0], i1 = sv_lds[wl][jj + 1];
      int i2 = sv_lds[wl][jj + 2], i3 = sv_lds[wl][jj + 3];
      float wA = w_lds[wl][jj + 0][head], wB = w_lds[wl][jj + 1][head];
      float wC = w_lds[wl][jj + 2][head], wD = w_lds[wl][jj + 3][head];
      float2 h0 = *(const float2*)(h + (size_t)i0 * HC + lane * 2);
      float2 h1 = *(const float2*)(h + (size_t)i1 * HC + lane * 2);
      float2 h2 = *(const float2*)(h + (size_t)i2 * HC + lane * 2);
      float2 h3 = *(const float2*)(h + (size_t)i3 * HC + lane * 2);
      ax += wA * h0.x; ay += wA * h0.y;
      ax += wB * h1.x; ay += wB * h1.y;
      ax += wC * h2.x; ay += wC * h2.y;
      ax += wD * h3.x; ay += wD * h3.y;
    }
    for (; jj < deg; jj++) {
      int i0 = sv_lds[wl][jj];
      float wA = w_lds[wl][jj][head];
      float2 h0 = *(const float2*)(h + (size_t)i0 * HC + lane * 2);
      ax += wA * h0.x; ay += wA * h0.y;
    }
  } else {
    // rare generic path (deg > 64): chunked two-pass
    float M0 = -1e30f, M1 = -1e30f, M2 = -1e30f, M3 = -1e30f;
    for (int c = lo; c < hi; c += 64) {
      int j = c + lane;
      int sv = (j < hi) ? csr_src[j] : 0;
      float4 a4 = ((const float4*)asrc)[sv];
      bool valid = (j < hi);
      float e0 = valid ? lrelu(a4.x + ad4.x) : -1e30f;
      float e1 = valid ? lrelu(a4.y + ad4.y) : -1e30f;
      float e2 = valid ? lrelu(a4.z + ad4.z) : -1e30f;
      float e3 = valid ? lrelu(a4.w + ad4.w) : -1e30f;
      BFLY_MAX4(e0, e1, e2, e3)
      M0 = fmaxf(M0, e0); M1 = fmaxf(M1, e1);
      M2 = fmaxf(M2, e2); M3 = fmaxf(M3, e3);
    }
    float S0 = 0.f, S1 = 0.f, S2 = 0.f, S3 = 0.f;
    for (int c = lo; c < hi; c += 64) {
      int j = c + lane;
      int sv = (j < hi) ? csr_src[j] : 0;
      float4 a4 = ((const float4*)asrc)[sv];
      bool valid = (j < hi);
      float e0 = valid ? lrelu(a4.x + ad4.x) : -1e30f;
      float e1 = valid ? lrelu(a4.y + ad4.y) : -1e30f;
      float e2 = valid ? lrelu(a4.z + ad4.z) : -1e30f;
      float e3 = valid ? lrelu(a4.w + ad4.w) : -1e30f;
      float w0 = expf(e0 - M0), w1 = expf(e1 - M1);
      float w2 = expf(e2 - M2), w3 = expf(e3 - M3);
      float s0 = w0, s1 = w1, s2 = w2, s3 = w3;
      BFLY_SUM4(s0, s1, s2, s3)
      S0 += s0; S1 += s1; S2 += s2; S3 += s3;
      sv_lds[wl][lane] = sv;
      *(float4*)&w_lds[wl][lane][0] = make_float4(w0, w1, w2, w3);
      int cnt = (hi - c < 64) ? (hi - c) : 64;
      int jj = 0;
      for (; jj + 4 <= cnt; jj += 4) {
        int i0 = sv_lds[wl][jj + 0], i1 = sv_lds[wl][jj + 1];
        int i2 = sv_lds[wl][jj + 2], i3 = sv_lds[wl][jj + 3];
        float wA = w_lds[wl][jj + 0][head], wB = w_lds[wl][jj + 1][head];
        float wC = w_lds[wl][jj + 2][head], wD = w_lds[wl][jj + 3][head];
        float2 h0 = *(const float2*)(h + (size_t)i0 * HC + lane * 2);
        float2 h1 = *(const float2*)(h + (size_t)i1 * HC + lane * 2);
        float2 h2 = *(const float2*)(h + (size_t)i2 * HC + lane * 2);
        float2 h3 = *(const float2*)(h + (size_t)i3 * HC + lane * 2);
        ax += wA * h0.x; ay += wA * h0.y;
        ax += wB * h1.x; ay += wB * h1.y;
        ax += wC * h2.x; ay += wC * h2.y;
        ax += wD * h3.x; ay += wD * h3.y;
      }
      for (; jj < cnt; jj++) {
        int i0 = sv_lds[wl][jj];
        float wA = w_lds[wl][jj][head];
        float2 h0 = *(const float2*)(h + (size_t)i0 * HC + lane * 2);
        ax += wA * h0.x; ay += wA * h0.y;
      }
    }
    S = (head == 0) ? S0 : (head == 1) ? S1 : (head == 2) ? S2 : S3;
  }

  float rden = 1.f / S;
  float2 b = *(const float2*)(bias + lane * 2);
  float vx = fmaxf(ax * rden + b.x, 0.f);
  float vy = fmaxf(ay * rden + b.y, 0.f);
  *(float2*)(out_h + (size_t)node * HC + lane * 2) = make_float2(vx, vy);
  if (do_pool) {
    int g = batch[node];
    unsigned* pp = pooled + g * HC + lane * 2;
    // post-relu values >= 0: bit compare == float compare; init 0 matches the
    // reference's where(isfinite, pooled, 0) empty-graph guard.
    atomicMax(pp + 0, __float_as_uint(vx));
    atomicMax(pp + 1, __float_as_uint(vy));
  }
}

// final head: out[g] = (pooled[g] @ Wlin + blin) @ Wout + bout ; 1 block/graph
__global__ __launch_bounds__(256) void k_mlp(
    const float* __restrict__ pooled, const float* __restrict__ Wlin,
    const float* __restrict__ blin, const float* __restrict__ Wout,
    const float* __restrict__ bout, float* __restrict__ out) {
  __shared__ float p[HC];
  __shared__ float z[LIN];
  int g = blockIdx.x, tid = threadIdx.x;
  if (tid < HC) p[tid] = pooled[g * HC + tid];
  __syncthreads();
  float zv = blin[tid];
  for (int k = 0; k < HC; k++) zv += p[k] * Wlin[k * LIN + tid];
  z[tid] = zv;
  __syncthreads();
  if (tid < OUTC) {
    float o = bout[tid];
    for (int k = 0; k < LIN; k++) o += z[k] * Wout[k * OUTC + tid];
    out[g * OUTC + tid] = o;
  }
}

extern "C" void kernel_launch(void* const* d_in, const int* in_sizes, int n_in,
                              void* d_out, int out_size, void* d_ws, size_t ws_size,
                              hipStream_t stream) {
  const float* x     = (const float*)d_in[0];
  const int*   ei    = (const int*)d_in[1];
  const int*   batch = (const int*)d_in[2];
  const float* Wl[3] = {(const float*)d_in[3], (const float*)d_in[7], (const float*)d_in[11]};
  const float* As[3] = {(const float*)d_in[4], (const float*)d_in[8], (const float*)d_in[12]};
  const float* Ad[3] = {(const float*)d_in[5], (const float*)d_in[9], (const float*)d_in[13]};
  const float* Bi[3] = {(const float*)d_in[6], (const float*)d_in[10], (const float*)d_in[14]};
  const float* Wlin  = (const float*)d_in[15];
  const float* blin  = (const float*)d_in[16];
  const float* Wout  = (const float*)d_in[17];
  const float* bout  = (const float*)d_in[18];
  float* out = (float*)d_out;

  // workspace layout (float offsets), total ~14.21M floats = ~56.8 MB
  float* ws = (float*)d_ws;
  float*    h       = ws;                          // N*128
  float*    nodeB   = ws + 6400000;                // N*128
  float*    asrc    = ws + 12800000;               // N*4
  float*    adst    = ws + 13000000;               // N*4
  int*      deg     = (int*)(ws + 13200000);       // N
  int*      cnt     = (int*)(ws + 13250000);       // N (adjacent to deg)
  int*      row_off = (int*)(ws + 13300000);       // N+1
  int*      csr_src = (int*)(ws + 13350008);       // E_TOT
  unsigned* pooled  = (unsigned*)(ws + 14200008);  // 64*128

  const int* srcp = ei;
  const int* dstp = ei + E_EDGES;

  hipMemsetAsync(deg, 0, 2 * N_NODES * sizeof(int), stream);
  hipMemsetAsync(pooled, 0, NG * HC * sizeof(unsigned), stream);

  // CSR by dst — built once, reused by all 3 layers
  k_hist<<<(E_TOT + 255) / 256, 256, 0, stream>>>(dstp, deg);
  k_scan<<<1, 1024, 0, stream>>>(deg, row_off);
  k_scatter<<<(E_TOT + 255) / 256, 256, 0, stream>>>(srcp, dstp, row_off, cnt, csr_src);

  const float* lin_in = x;
  for (int L = 0; L < 3; L++) {
    k_gemm_alpha<<<(N_NODES + 127) / 128, 256, 0, stream>>>(
        lin_in, Wl[L], As[L], Ad[L], h, asrc, adst);
    k_aggr<<<(N_NODES * 64 + 255) / 256, 256, 0, stream>>>(
        row_off, csr_src, asrc, adst, h, Bi[L], batch,
        nodeB, pooled, (L == 2) ? 1 : 0);
    lin_in = nodeB;
  }
  k_mlp<<<NG, 256, 0, stream>>>((const float*)pooled, Wlin, blin, Wout, bout, out);
}